// Round 8
// baseline (282.651 us; speedup 1.0000x reference)
//
#include <hip/hip_runtime.h>
#include <hip/hip_bf16.h>
#include <math.h>

#define N 8192
#define H 64
#define B 8
#define MAXDEG 128
#define REPS 16
#define NBLK 512
#define NTHR 256
#define GSIZE (NBLK * NTHR)      // 131072
#define NWAVE (NBLK * 4)         // 2048 waves
#define RPW   (N / NWAVE)        // 4 rows per wave in spmm phase

// ---- workspace layout (bytes) ----
// zeroed by P0 (in-kernel): [0, ZERO_END)
#define OFF_MASK 0ULL            // 8192*8192/8 = 8,388,608
#define OFF_CNT  8388608ULL      // 8192 u32 = 32768
#define OFF_WR   8421376ULL      // REPS*8*64 f32 = 32768
#define OFF_PR   8454144ULL      // 32768
#define OFF_NL   8486912ULL      // 8 f32 + pad = 64
#define ZERO_END 8486976ULL      // /16 = 530,436 float4
// zeroed by k_bar0 each call:
#define OFF_BAR  8486976ULL      // 4 u32 + pad = 64
// not zeroed:
#define OFF_COLS 8487040ULL      // 8192*128 u16 = 2,097,152
#define OFF_TGT  10584192ULL     // 512 f32 = 2048
#define OFF_UV   10586240ULL     // 3*64 f32 = 768
#define OFF_XD   10587008ULL     // 8192*32 f32 = 1,048,576 (16B aligned)
#define OFF_PD   11635584ULL     // 8192*64 bf16 = 1,048,576
// end ~12.1 MB

__device__ __forceinline__ float bf2f(unsigned short u) {
    return __uint_as_float(((unsigned)u) << 16);
}

// Manual grid barrier: release-arrive + acquire-spin (agent scope flushes /
// invalidates per-XCD L2 — same primitives cooperative grid.sync uses).
__device__ __forceinline__ void gbar(unsigned* c) {
    __syncthreads();
    if (threadIdx.x == 0) {
        __hip_atomic_fetch_add(c, 1u, __ATOMIC_ACQ_REL, __HIP_MEMORY_SCOPE_AGENT);
        while (__hip_atomic_load(c, __ATOMIC_ACQUIRE, __HIP_MEMORY_SCOPE_AGENT) < (unsigned)NBLK)
            __builtin_amdgcn_s_sleep(2);
    }
    __syncthreads();
}

// Tiny: zero the 4 barrier counters (handles first-call 0xAA poison)
__global__ __launch_bounds__(64) void k_bar0(unsigned* __restrict__ bar) {
    if (threadIdx.x < 16) bar[threadIdx.x] = 0u;
}

__global__ __launch_bounds__(NTHR, 2) void k_fused(
    const float* __restrict__ x, const int* __restrict__ ei, int nE,
    const int* __restrict__ target, const float* __restrict__ pmask,
    const float* __restrict__ ne, const float* __restrict__ W_sp,
    const float* __restrict__ b_sp, const float* __restrict__ W_g,
    const float* __restrict__ b_g, const float* __restrict__ W_d,
    const float* __restrict__ b_d, const float* __restrict__ W_a,
    const float* __restrict__ b_a, const float* __restrict__ prereq_w,
    char* __restrict__ ws, float* __restrict__ out)
{
    __shared__ float wgs[H * 65];                 // 16.6 KB padded W_g
    __shared__ __align__(16) float hv[16 * H];    // 4 KB: 16 ne rows

    unsigned*       bits = (unsigned*)(ws + OFF_MASK);
    unsigned*       cnt  = (unsigned*)(ws + OFF_CNT);
    float*          wr_  = (float*)(ws + OFF_WR);
    float*          pr_  = (float*)(ws + OFF_PR);
    float*          nlac = (float*)(ws + OFF_NL);
    unsigned*       bar  = (unsigned*)(ws + OFF_BAR);
    unsigned short* cols = (unsigned short*)(ws + OFF_COLS);
    float*          tgt  = (float*)(ws + OFF_TGT);
    float*          uvec = (float*)(ws + OFF_UV);
    float*          xd   = (float*)(ws + OFF_XD);
    __hip_bfloat16* Pd   = (__hip_bfloat16*)(ws + OFF_PD);

    const int tid  = threadIdx.x;
    const int lane = tid & 63;
    const int wv   = tid >> 6;
    const int bid  = blockIdx.x;
    const int gid  = bid * NTHR + tid;
    const int wid  = bid * 4 + wv;               // [0, NWAVE)

    // ---- P0: zero mask+cnt+accumulators (ws poisoned once; zero every call) ----
    {
        float4* z = (float4*)ws;
        const float4 f0 = make_float4(0.f, 0.f, 0.f, 0.f);
        for (unsigned i = gid; i < (unsigned)(ZERO_END / 16); i += GSIZE) z[i] = f0;
    }
    gbar(&bar[0]);

    // ---- P1: one-pass dedup edge append via N^2 bitmask ----
    for (int e = gid; e < nE; e += GSIZE) {
        int r = ei[e];
        int c = ei[nE + e];
        unsigned bitidx = (unsigned)r * (unsigned)N + (unsigned)c;   // < 2^26
        unsigned bit = 1u << (bitidx & 31u);
        unsigned old = atomicOr(&bits[bitidx >> 5], bit);
        if (!(old & bit)) {
            unsigned k = atomicAdd(&cnt[r], 1u);
            if (k < MAXDEG) cols[r * MAXDEG + k] = (unsigned short)c;
        }
    }
    gbar(&bar[1]);

    // ---- P2: prep Pd (all blocks, 16 nodes each) + uvec (block 0) + xd ----
    for (int e = tid; e < H * H; e += NTHR)
        wgs[(e >> 6) * 65 + (e & 63)] = W_g[e];
    {
        const float* nebase = ne + (size_t)bid * 16 * H;
        for (int j = 0; j < 4; ++j) hv[tid + j * NTHR] = nebase[tid + j * NTHR];
    }
    __syncthreads();
    {
        float wr[H];
#pragma unroll
        for (int k = 0; k < H; ++k) wr[k] = wgs[lane * 65 + k];

        if (bid == 0 && wv == 0) {   // uvec = {W_g@Wsp0, W_g@Wsp1, W_g@b_sp}
            float v0 = W_sp[lane * 2 + 0], v1 = W_sp[lane * 2 + 1], vb = b_sp[lane];
            float a0 = 0.f, a1 = 0.f, a2 = 0.f;
#pragma unroll
            for (int k = 0; k < H; ++k) {
                a0 = fmaf(wr[k], __shfl(v0, k, 64), a0);
                a1 = fmaf(wr[k], __shfl(v1, k, 64), a1);
                a2 = fmaf(wr[k], __shfl(vb, k, 64), a2);
            }
            uvec[lane] = a0; uvec[64 + lane] = a1; uvec[128 + lane] = a2;
        }

        for (int ii = 0; ii < 4; ++ii) {         // 4 nodes per wave
            const int node = wv * 4 + ii;
            const int m = bid * 16 + node;
            const float4* h4p = (const float4*)&hv[node * H];
            float acc = 0.f;
#pragma unroll
            for (int kk = 0; kk < 16; ++kk) {
                float4 h4 = h4p[kk];
                acc = fmaf(wr[4 * kk + 0], h4.x, acc);
                acc = fmaf(wr[4 * kk + 1], h4.y, acc);
                acc = fmaf(wr[4 * kk + 2], h4.z, acc);
                acc = fmaf(wr[4 * kk + 3], h4.w, acc);
            }
            float dis = rsqrtf((float)(cnt[m] + 1u));
            Pd[m * H + lane] = __float2bfloat16(dis * acc);
        }
    }
    // xd on the last 32 blocks (8192 threads, one node each)
    if (bid >= NBLK - 32) {
        const int m = (bid - (NBLK - 32)) * NTHR + tid;
        float dis = rsqrtf((float)(cnt[m] + 1u));
        float row[32];
#pragma unroll
        for (int j = 0; j < 32; ++j) row[j] = 0.f;
        row[16] = dis;
#pragma unroll
        for (int b = 0; b < B; ++b) {
            float2 xv = ((const float2*)x)[b * N + m];
            row[b]      = dis * xv.x;
            row[8 + b]  = dis * xv.y;
            row[17 + b] = pmask[b * N + m];
            float s = xv.x;                       // n_learned partial
            for (int off = 32; off; off >>= 1) s += __shfl_down(s, off, 64);
            if (lane == 0) atomicAdd(&nlac[b], s);
        }
        float4* dst = (float4*)&xd[m * 32];
#pragma unroll
        for (int j = 0; j < 8; ++j)
            dst[j] = make_float4(row[4 * j], row[4 * j + 1], row[4 * j + 2], row[4 * j + 3]);
    }
    gbar(&bar[2]);

    // ---- P3: batch-collapsed sparse gather + z reconstruction + reductions ----
    {
        const float u0 = uvec[lane], u1 = uvec[64 + lane], ub = uvec[128 + lane];
        const float bg = b_g[lane];
        int tg[B];
#pragma unroll
        for (int b = 0; b < B; ++b) tg[b] = target[b];
        float wa[B], pa[B];
#pragma unroll
        for (int b = 0; b < B; ++b) { wa[b] = 0.f; pa[b] = 0.f; }

        for (int i = 0; i < RPW; ++i) {
            const int r = wid * RPW + i;
            float rloc = xd[r * 32 + (lane & 31)];
            float sp = bf2f(((const unsigned short*)Pd)[r * H + lane]);  // eye term
            float sx = rloc;
            const int kc = min((int)cnt[r], MAXDEG);
            const unsigned short* cl = &cols[r * MAXDEG];
#pragma unroll 4
            for (int k = 0; k < kc; ++k) {
                int c = (int)cl[k];
                sp += bf2f(((const unsigned short*)Pd)[c * H + lane]);
                sx += xd[c * 32 + (lane & 31)];
            }
            const float dis_r = __shfl(rloc, 16, 64);
            const float rdis = 1.0f / dis_r;
            const float sd = __shfl(sx, 16, 64);
            const float base = fmaf(sd, ub, sp);
#pragma unroll
            for (int b = 0; b < B; ++b) {
                float sx0 = __shfl(sx, b, 64);
                float sx1 = __shfl(sx, 8 + b, 64);
                float sc  = __shfl(rloc, 8 + b, 64) * rdis;   // score = x1
                float mk  = __shfl(rloc, 17 + b, 64);
                float v = fmaf(sx0, u0, fmaf(sx1, u1, base));
                float z = fmaxf(fmaf(dis_r, v, bg), 0.f);
                wa[b] = fmaf(z, sc, wa[b]);
                float spl = z + __logf(1.f + __expf(-z));     // softplus, z>=0
                pa[b] = fmaf(spl, mk, pa[b]);
                if (r == tg[b]) tgt[b * H + lane] = z;
            }
        }
        const int rep = wid & (REPS - 1);
#pragma unroll
        for (int b = 0; b < B; ++b) {
            atomicAdd(&wr_[(rep * B + b) * H + lane], wa[b]);
            atomicAdd(&pr_[(rep * B + b) * H + lane], pa[b]);
        }
    }

    // ---- final barrier: everyone arrives; only block 0 waits and finishes ----
    __syncthreads();
    if (tid == 0)
        __hip_atomic_fetch_add(&bar[3], 1u, __ATOMIC_ACQ_REL, __HIP_MEMORY_SCOPE_AGENT);
    if (bid != 0) return;
    if (tid == 0) {
        while (__hip_atomic_load(&bar[3], __ATOMIC_ACQUIRE, __HIP_MEMORY_SCOPE_AGENT) < (unsigned)NBLK)
            __builtin_amdgcn_s_sleep(2);
    }
    __syncthreads();

    // ---- P4: reduce replicas + final dots + sigmoid (block 0 only) ----
    {
        const int h = lane;
        for (int bb = wv; bb < B; bb += 4) {
            float wsum = 0.f, psum = 0.f;
#pragma unroll
            for (int rep = 0; rep < REPS; ++rep) {
                wsum += wr_[(rep * B + bb) * H + h];
                psum += pr_[(rep * B + bb) * H + h];
            }
            float nl = fmaxf(nlac[bb], 1.0f);
            float ap = (wsum / nl) * W_a[h];
            float dp = tgt[bb * H + h] * W_d[h];
            float pp = psum;
            for (int off = 32; off; off >>= 1) {
                ap += __shfl_down(ap, off, 64);
                dp += __shfl_down(dp, off, 64);
                pp += __shfl_down(pp, off, 64);
            }
            if (h == 0) {
                float ability    = ap + b_a[0];
                float difficulty = dp + b_d[0];
                float preq       = fabsf(prereq_w[0]) * (pp * (1.0f / (float)H));
                float gap  = ability - difficulty + preq;
                float prob = 1.0f / (1.0f + __expf(-gap));
                out[bb]     = prob;
                out[B + bb] = gap;
            }
        }
    }
}

extern "C" void kernel_launch(void* const* d_in, const int* in_sizes, int n_in,
                              void* d_out, int out_size, void* d_ws, size_t ws_size,
                              hipStream_t stream) {
    const float* x        = (const float*)d_in[0];
    const int*   ei       = (const int*)d_in[1];
    const int*   target   = (const int*)d_in[2];
    const float* pmask    = (const float*)d_in[3];
    const float* ne       = (const float*)d_in[4];
    const float* W_sp     = (const float*)d_in[5];
    const float* b_sp     = (const float*)d_in[6];
    const float* W_g      = (const float*)d_in[7];
    const float* b_g      = (const float*)d_in[8];
    const float* W_d      = (const float*)d_in[9];
    const float* b_d      = (const float*)d_in[10];
    const float* W_a      = (const float*)d_in[11];
    const float* b_a      = (const float*)d_in[12];
    const float* prereq_w = (const float*)d_in[13];

    const int nE = in_sizes[1] / 2;
    char*  ws  = (char*)d_ws;
    float* out = (float*)d_out;

    k_bar0<<<1, 64, 0, stream>>>((unsigned*)(ws + OFF_BAR));
    k_fused<<<NBLK, NTHR, 0, stream>>>(x, ei, nE, target, pmask, ne, W_sp, b_sp,
                                       W_g, b_g, W_d, b_d, W_a, b_a, prereq_w,
                                       ws, out);
}

// Round 9
// 143.671 us; speedup vs baseline: 1.9673x; 1.9673x over previous
//
#include <hip/hip_runtime.h>
#include <hip/hip_bf16.h>
#include <math.h>

#define N 8192
#define H 64
#define B 8
#define MAXDEG 128
#define REPS 16
#define NBLK 512
#define NTHR 256
#define GSIZE (NBLK * NTHR)      // 131072
#define NWAVE (NBLK * 4)         // 2048 waves
#define RPW   (N / NWAVE)        // 4 rows per wave in spmm phase

// ---- workspace layout (bytes) ----
// zeroed each call by k_zero (dispatch 1):
#define OFF_CNT  0ULL            // 8192 u32 = 32768
#define OFF_WR   32768ULL        // REPS*8*64 f32 = 32768
#define OFF_PR   65536ULL        // 32768
#define OFF_NLR  98304ULL        // REPS*8 f32 = 512
#define OFF_BAR  98816ULL        // 4 u32 + pad = 64
#define ZERO_END 98880ULL        // /16 = 6180 float4
// not zeroed:
#define OFF_COLS 98880ULL        // 8192*128 u16 = 2,097,152
#define OFF_TGT  2196032ULL      // 512 f32 = 2048
#define OFF_UV   2198080ULL      // 3*64 f32 = 768
#define OFF_XD   2198848ULL      // 8192*32 f32 = 1,048,576 (16B aligned)
#define OFF_PD   3247424ULL      // 8192*64 bf16 = 1,048,576
// end ~4.3 MB

__device__ __forceinline__ float bf2f(unsigned short u) {
    return __uint_as_float(((unsigned)u) << 16);
}

// Grid barrier, cheap-spin version:
//  - arrive: fetch_add(RELEASE, agent) -> one L2 writeback of this block's stores
//  - spin:   RELAXED agent loads (sc1 bypass, NO per-iteration invalidate)
//  - exit:   one ACQUIRE load -> single L1/L2 invalidate
// R8's version did an ACQUIRE (buffer_inv + waitcnt) EVERY poll -> 272us.
__device__ __forceinline__ void gbar(unsigned* c) {
    __syncthreads();
    if (threadIdx.x == 0) {
        __hip_atomic_fetch_add(c, 1u, __ATOMIC_RELEASE, __HIP_MEMORY_SCOPE_AGENT);
        while (__hip_atomic_load(c, __ATOMIC_RELAXED, __HIP_MEMORY_SCOPE_AGENT) < (unsigned)NBLK)
            __builtin_amdgcn_s_sleep(8);
        (void)__hip_atomic_load(c, __ATOMIC_ACQUIRE, __HIP_MEMORY_SCOPE_AGENT);
    }
    __syncthreads();
}

// Dispatch 1: zero cnt + replica accumulators + barrier counters (99 KB).
__global__ __launch_bounds__(256) void k_zero(float4* __restrict__ p) {
    unsigned i = blockIdx.x * 256u + threadIdx.x;
    if (i < (unsigned)(ZERO_END / 16))
        p[i] = make_float4(0.f, 0.f, 0.f, 0.f);
}

__global__ __launch_bounds__(NTHR, 2) void k_fused(
    const float* __restrict__ x, const int* __restrict__ ei, int nE,
    const int* __restrict__ target, const float* __restrict__ pmask,
    const float* __restrict__ ne, const float* __restrict__ W_sp,
    const float* __restrict__ b_sp, const float* __restrict__ W_g,
    const float* __restrict__ b_g, const float* __restrict__ W_d,
    const float* __restrict__ b_d, const float* __restrict__ W_a,
    const float* __restrict__ b_a, const float* __restrict__ prereq_w,
    char* __restrict__ ws, float* __restrict__ out)
{
    __shared__ float wgs[H * 65];                 // 16.6 KB padded W_g
    __shared__ __align__(16) float hv[16 * H];    // 4 KB: 16 ne rows
    __shared__ unsigned short ls[4][MAXDEG];      // 1 KB dedup staging

    unsigned*       cnt  = (unsigned*)(ws + OFF_CNT);
    float*          wr_  = (float*)(ws + OFF_WR);
    float*          pr_  = (float*)(ws + OFF_PR);
    float*          nlr  = (float*)(ws + OFF_NLR);
    unsigned*       bar  = (unsigned*)(ws + OFF_BAR);
    unsigned short* cols = (unsigned short*)(ws + OFF_COLS);
    float*          tgt  = (float*)(ws + OFF_TGT);
    float*          uvec = (float*)(ws + OFF_UV);
    float*          xd   = (float*)(ws + OFF_XD);
    __hip_bfloat16* Pd   = (__hip_bfloat16*)(ws + OFF_PD);

    const int tid  = threadIdx.x;
    const int lane = tid & 63;
    const int wv   = tid >> 6;
    const int bid  = blockIdx.x;
    const int gid  = bid * NTHR + tid;
    const int wid  = bid * 4 + wv;               // [0, NWAVE)

    // ---- P1: append edges (dedup in P2) ----
    for (int e = gid; e < nE; e += GSIZE) {
        int r = ei[e];
        int c = ei[nE + e];
        unsigned k = atomicAdd(&cnt[r], 1u);
        if (k < MAXDEG) cols[r * MAXDEG + k] = (unsigned short)c;
    }
    gbar(&bar[0]);

    // ---- P2: per-wave {dedup -> dis -> xd -> Pd} for 4 rows; uvec on blk0 ----
    for (int e = tid; e < H * H; e += NTHR)
        wgs[(e >> 6) * 65 + (e & 63)] = W_g[e];
    {
        const float* nebase = ne + (size_t)bid * 16 * H;
        for (int j = 0; j < 4; ++j) hv[tid + j * NTHR] = nebase[tid + j * NTHR];
    }
    __syncthreads();

    float wr[H];
#pragma unroll
    for (int k = 0; k < H; ++k) wr[k] = wgs[lane * 65 + k];

    if (bid == 0 && wv == 0) {   // uvec = {W_g@Wsp0, W_g@Wsp1, W_g@b_sp}
        float v0 = W_sp[lane * 2 + 0], v1 = W_sp[lane * 2 + 1], vb = b_sp[lane];
        float a0 = 0.f, a1 = 0.f, a2 = 0.f;
#pragma unroll
        for (int k = 0; k < H; ++k) {
            a0 = fmaf(wr[k], __shfl(v0, k, 64), a0);
            a1 = fmaf(wr[k], __shfl(v1, k, 64), a1);
            a2 = fmaf(wr[k], __shfl(vb, k, 64), a2);
        }
        uvec[lane] = a0; uvec[64 + lane] = a1; uvec[128 + lane] = a2;
    }

    for (int i = 0; i < 4; ++i) {
        const int r = bid * 16 + wv * 4 + i;
        // --- dedup row r (R4-proven LDS form); tot = distinct count ---
        const int kraw = min((int)cnt[r], MAXDEG);
        unsigned short* cl = &cols[r * MAXDEG];
        for (int t = lane; t < kraw; t += 64) ls[wv][t] = cl[t];
        int c0 = (lane < kraw) ? (int)ls[wv][lane] : -1;
        int dup0 = 0;
        for (int j = 0; j < lane && j < kraw; ++j)
            dup0 |= ((int)ls[wv][j] == c0);
        unsigned long long m0 = __ballot((lane < kraw) && !dup0);
        unsigned long long below = (1ULL << lane) - 1ULL;
        unsigned tot = __popcll(m0);
        if ((lane < kraw) && !dup0)
            cl[__popcll(m0 & below)] = (unsigned short)c0;
        if (kraw > 64) {                          // wave-uniform, rare
            const int i1 = lane + 64;
            int c1 = (i1 < kraw) ? (int)ls[wv][i1] : -2;
            int dup1 = 0;
            for (int j = 0; j < i1 && j < kraw; ++j)
                dup1 |= ((int)ls[wv][j] == c1);
            unsigned long long m1 = __ballot((i1 < kraw) && !dup1);
            if ((i1 < kraw) && !dup1)
                cl[tot + __popcll(m1 & below)] = (unsigned short)c1;
            tot += __popcll(m1);
        }
        if (lane == 0) cnt[r] = tot;
        const float dis = rsqrtf((float)(tot + 1u));   // register count, no reload

        // --- xd row r: [0..7]=dis*x0_b, [8..15]=dis*x1_b, [16]=dis, [17..24]=pm ---
        float xvx = 0.f, xvy = 0.f, pm = 0.f;
        if (lane < 8) {
            float2 t2 = ((const float2*)x)[lane * N + r];
            xvx = t2.x; xvy = t2.y;
        }
        if (lane >= 17 && lane < 25) pm = pmask[(lane - 17) * N + r];
        float yv = __shfl(xvy, lane & 7, 64);          // lanes 8..15 <- lanes 0..7
        float val = (lane < 8)  ? dis * xvx
                  : (lane < 16) ? dis * yv
                  : (lane == 16) ? dis
                  : (lane < 25) ? pm : 0.f;
        if (lane < 32) xd[r * 32 + lane] = val;

        // --- Pd row r: dis * (W_g @ ne[r]) in bf16 ---
        const float4* h4p = (const float4*)&hv[(wv * 4 + i) * H];
        float acc = 0.f;
#pragma unroll
        for (int kk = 0; kk < 16; ++kk) {
            float4 h4 = h4p[kk];
            acc = fmaf(wr[4 * kk + 0], h4.x, acc);
            acc = fmaf(wr[4 * kk + 1], h4.y, acc);
            acc = fmaf(wr[4 * kk + 2], h4.z, acc);
            acc = fmaf(wr[4 * kk + 3], h4.w, acc);
        }
        Pd[r * H + lane] = __float2bfloat16(dis * acc);
    }
    gbar(&bar[1]);

    // ---- P3: batch-collapsed sparse gather + z reconstruction + reductions ----
    {
        const float u0 = uvec[lane], u1 = uvec[64 + lane], ub = uvec[128 + lane];
        const float bg = b_g[lane];
        int tg[B];
#pragma unroll
        for (int b = 0; b < B; ++b) tg[b] = target[b];
        float wa[B], pa[B];
#pragma unroll
        for (int b = 0; b < B; ++b) { wa[b] = 0.f; pa[b] = 0.f; }
        float nla = 0.f;                         // lanes 0..7: n_learned partial

        for (int i = 0; i < RPW; ++i) {
            const int r = wid * RPW + i;
            float rloc = xd[r * 32 + (lane & 31)];
            float sp = bf2f(((const unsigned short*)Pd)[r * H + lane]);  // eye term
            float sx = rloc;
            const int kc = min((int)cnt[r], MAXDEG);
            const unsigned short* cl = &cols[r * MAXDEG];
#pragma unroll 4
            for (int k = 0; k < kc; ++k) {
                int c = (int)cl[k];
                sp += bf2f(((const unsigned short*)Pd)[c * H + lane]);
                sx += xd[c * 32 + (lane & 31)];
            }
            const float dis_r = __shfl(rloc, 16, 64);
            const float rdis = 1.0f / dis_r;
            nla = fmaf(rloc, rdis, nla);         // lanes<8: x0_b of own row
            const float sd = __shfl(sx, 16, 64);
            const float base = fmaf(sd, ub, sp);
#pragma unroll
            for (int b = 0; b < B; ++b) {
                float sx0 = __shfl(sx, b, 64);
                float sx1 = __shfl(sx, 8 + b, 64);
                float sc  = __shfl(rloc, 8 + b, 64) * rdis;   // score = x1
                float mk  = __shfl(rloc, 17 + b, 64);
                float v = fmaf(sx0, u0, fmaf(sx1, u1, base));
                float z = fmaxf(fmaf(dis_r, v, bg), 0.f);
                wa[b] = fmaf(z, sc, wa[b]);
                float spl = z + __logf(1.f + __expf(-z));     // softplus, z>=0
                pa[b] = fmaf(spl, mk, pa[b]);
                if (r == tg[b]) tgt[b * H + lane] = z;
            }
        }
        const int rep = wid & (REPS - 1);
#pragma unroll
        for (int b = 0; b < B; ++b) {
            atomicAdd(&wr_[(rep * B + b) * H + lane], wa[b]);
            atomicAdd(&pr_[(rep * B + b) * H + lane], pa[b]);
        }
        if (lane < 8) atomicAdd(&nlr[rep * 8 + lane], nla);
    }

    // ---- final partial barrier: all arrive (release); only block 0 waits ----
    __syncthreads();
    if (tid == 0)
        __hip_atomic_fetch_add(&bar[2], 1u, __ATOMIC_RELEASE, __HIP_MEMORY_SCOPE_AGENT);
    if (bid != 0) return;
    if (tid == 0) {
        while (__hip_atomic_load(&bar[2], __ATOMIC_RELAXED, __HIP_MEMORY_SCOPE_AGENT) < (unsigned)NBLK)
            __builtin_amdgcn_s_sleep(8);
        (void)__hip_atomic_load(&bar[2], __ATOMIC_ACQUIRE, __HIP_MEMORY_SCOPE_AGENT);
    }
    __syncthreads();

    // ---- P4: reduce replicas + final dots + sigmoid (block 0 only) ----
    {
        const int h = lane;
        for (int bb = wv; bb < B; bb += 4) {
            float wsum = 0.f, psum = 0.f, nlv = 0.f;
#pragma unroll
            for (int rep = 0; rep < REPS; ++rep) {
                wsum += wr_[(rep * B + bb) * H + h];
                psum += pr_[(rep * B + bb) * H + h];
                nlv  += nlr[rep * 8 + bb];
            }
            float nl = fmaxf(nlv, 1.0f);
            float ap = (wsum / nl) * W_a[h];
            float dp = tgt[bb * H + h] * W_d[h];
            float pp = psum;
            for (int off = 32; off; off >>= 1) {
                ap += __shfl_down(ap, off, 64);
                dp += __shfl_down(dp, off, 64);
                pp += __shfl_down(pp, off, 64);
            }
            if (h == 0) {
                float ability    = ap + b_a[0];
                float difficulty = dp + b_d[0];
                float preq       = fabsf(prereq_w[0]) * (pp * (1.0f / (float)H));
                float gap  = ability - difficulty + preq;
                float prob = 1.0f / (1.0f + __expf(-gap));
                out[bb]     = prob;
                out[B + bb] = gap;
            }
        }
    }
}

extern "C" void kernel_launch(void* const* d_in, const int* in_sizes, int n_in,
                              void* d_out, int out_size, void* d_ws, size_t ws_size,
                              hipStream_t stream) {
    const float* x        = (const float*)d_in[0];
    const int*   ei       = (const int*)d_in[1];
    const int*   target   = (const int*)d_in[2];
    const float* pmask    = (const float*)d_in[3];
    const float* ne       = (const float*)d_in[4];
    const float* W_sp     = (const float*)d_in[5];
    const float* b_sp     = (const float*)d_in[6];
    const float* W_g      = (const float*)d_in[7];
    const float* b_g      = (const float*)d_in[8];
    const float* W_d      = (const float*)d_in[9];
    const float* b_d      = (const float*)d_in[10];
    const float* W_a      = (const float*)d_in[11];
    const float* b_a      = (const float*)d_in[12];
    const float* prereq_w = (const float*)d_in[13];

    const int nE = in_sizes[1] / 2;
    char*  ws  = (char*)d_ws;
    float* out = (float*)d_out;

    k_zero<<<(unsigned)(ZERO_END / 16 + 255) / 256, 256, 0, stream>>>((float4*)ws);
    k_fused<<<NBLK, NTHR, 0, stream>>>(x, ei, nE, target, pmask, ne, W_sp, b_sp,
                                       W_g, b_g, W_d, b_d, W_a, b_a, prereq_w,
                                       ws, out);
}

// Round 10
// 93.513 us; speedup vs baseline: 3.0226x; 1.5364x over previous
//
#include <hip/hip_runtime.h>
#include <hip/hip_fp16.h>
#include <math.h>

#define N 8192
#define H 64
#define B 8
#define MAXDEG 128
#define REPS 16

// ---- workspace layout (bytes) ----
// zeroed each call by k_zero:
#define OFF_CNT  0ULL            // 8192 u32 = 32768
#define OFF_WR   32768ULL        // REPS*8*64 f32 = 32768
#define OFF_PR   65536ULL        // 32768
#define OFF_NLR  98304ULL        // REPS*8 f32 = 512
#define ZERO_END 98816ULL        // /16 = 6176 float4
// not zeroed:
#define OFF_COLS 98816ULL        // 8192*128 u16 = 2,097,152
#define OFF_TGT  2195968ULL      // 512 f32 = 2048
#define OFF_UV   2198016ULL      // 3*64 f32 = 768
#define OFF_REC  2198784ULL      // 8192*64 u32 = 2,097,152 (256B-aligned)
// end ~4.3 MB

// K0: zero cnt + replica accumulators (~97 KB)
__global__ __launch_bounds__(256) void k_zero(float4* __restrict__ p) {
    unsigned i = blockIdx.x * 256u + threadIdx.x;
    if (i < (unsigned)(ZERO_END / 16))
        p[i] = make_float4(0.f, 0.f, 0.f, 0.f);
}

// K1: append edges (1 edge/thread; dedup in K2)
__global__ __launch_bounds__(256) void k_edges(const int* __restrict__ ei, int nE,
                                               unsigned* __restrict__ cnt,
                                               unsigned short* __restrict__ cols) {
    int e = blockIdx.x * 256 + threadIdx.x;
    if (e >= nE) return;
    int r = ei[e];
    int c = ei[nE + e];
    unsigned k = atomicAdd(&cnt[r], 1u);
    if (k < MAXDEG) cols[r * MAXDEG + k] = (unsigned short)c;
}

// K2: per-wave {dedup -> dis -> packed record} for 2 rows; uvec on blk0/wv0.
// rec[m][lane] u32 = f16(dis_m * (W_g@ne[m])_lane) << 16 | f16(aux_lane)
// aux: lane<8: dis*x0_b; 8..15: dis*x1_b; 16: dis; 17..24: pmask_b; else 0.
__global__ __launch_bounds__(256) void k_prep(const float* __restrict__ ne,
                                              const float* __restrict__ W_g,
                                              const float* __restrict__ W_sp,
                                              const float* __restrict__ b_sp,
                                              const float* __restrict__ x,
                                              const float* __restrict__ pmask,
                                              unsigned* __restrict__ cnt,
                                              unsigned short* __restrict__ cols,
                                              unsigned* __restrict__ rec,
                                              float* __restrict__ uvec) {
    __shared__ float wgs[H * 65];                // padded W_g
    __shared__ unsigned short ls[4][MAXDEG];     // dedup staging
    const int tid = threadIdx.x, lane = tid & 63, wv = tid >> 6;
    const int bid = blockIdx.x;

    for (int e = tid; e < H * H; e += 256)
        wgs[(e >> 6) * 65 + (e & 63)] = W_g[e];
    __syncthreads();

    float wr[H];
#pragma unroll
    for (int k = 0; k < H; ++k) wr[k] = wgs[lane * 65 + k];

    if (bid == 0 && wv == 0) {   // uvec = {W_g@Wsp0, W_g@Wsp1, W_g@b_sp}
        float v0 = W_sp[lane * 2 + 0], v1 = W_sp[lane * 2 + 1], vb = b_sp[lane];
        float a0 = 0.f, a1 = 0.f, a2 = 0.f;
#pragma unroll
        for (int k = 0; k < H; ++k) {
            a0 = fmaf(wr[k], __shfl(v0, k, 64), a0);
            a1 = fmaf(wr[k], __shfl(v1, k, 64), a1);
            a2 = fmaf(wr[k], __shfl(vb, k, 64), a2);
        }
        uvec[lane] = a0; uvec[64 + lane] = a1; uvec[128 + lane] = a2;
    }

    for (int i = 0; i < 2; ++i) {
        const int r = (bid * 4 + wv) * 2 + i;
        // --- dedup row r (R4/R9-proven LDS form) ---
        const int kraw = min((int)cnt[r], MAXDEG);
        unsigned short* cl = &cols[r * MAXDEG];
        for (int t = lane; t < kraw; t += 64) ls[wv][t] = cl[t];
        int c0 = (lane < kraw) ? (int)ls[wv][lane] : -1;
        int dup0 = 0;
        for (int j = 0; j < lane && j < kraw; ++j)
            dup0 |= ((int)ls[wv][j] == c0);
        unsigned long long m0 = __ballot((lane < kraw) && !dup0);
        unsigned long long below = (1ULL << lane) - 1ULL;
        unsigned tot = __popcll(m0);
        if ((lane < kraw) && !dup0)
            cl[__popcll(m0 & below)] = (unsigned short)c0;
        if (kraw > 64) {                          // wave-uniform, rare
            const int i1 = lane + 64;
            int c1 = (i1 < kraw) ? (int)ls[wv][i1] : -2;
            int dup1 = 0;
            for (int j = 0; j < i1 && j < kraw; ++j)
                dup1 |= ((int)ls[wv][j] == c1);
            unsigned long long m1 = __ballot((i1 < kraw) && !dup1);
            if ((i1 < kraw) && !dup1)
                cl[tot + __popcll(m1 & below)] = (unsigned short)c1;
            tot += __popcll(m1);
        }
        if (lane == 0) cnt[r] = tot;
        const float dis = rsqrtf((float)(tot + 1u));

        // --- aux for row r ---
        float xvx = 0.f, xvy = 0.f, pm = 0.f;
        if (lane < 8) {
            float2 t2 = ((const float2*)x)[lane * N + r];
            xvx = t2.x; xvy = t2.y;
        }
        if (lane >= 17 && lane < 25) pm = pmask[(lane - 17) * N + r];
        float yv = __shfl(xvy, lane & 7, 64);
        float aux = (lane < 8)   ? dis * xvx
                  : (lane < 16)  ? dis * yv
                  : (lane == 16) ? dis
                  : (lane < 25)  ? pm : 0.f;

        // --- P part: dis * (W_g @ ne[r])_lane (broadcast float4 reads) ---
        const float4* ne4 = (const float4*)(ne + (size_t)r * H);
        float acc = 0.f;
#pragma unroll
        for (int kk = 0; kk < 16; ++kk) {
            float4 h4 = ne4[kk];
            acc = fmaf(wr[4 * kk + 0], h4.x, acc);
            acc = fmaf(wr[4 * kk + 1], h4.y, acc);
            acc = fmaf(wr[4 * kk + 2], h4.z, acc);
            acc = fmaf(wr[4 * kk + 3], h4.w, acc);
        }
        unsigned w = ((unsigned)__half_as_ushort(__float2half(dis * acc)) << 16)
                   |  (unsigned)__half_as_ushort(__float2half(aux));
        rec[(size_t)r * 64 + lane] = w;
    }
}

// K3: gather phase — 1 row/wave, 8192 waves, 1 load per neighbor (256B coalesced).
__global__ __launch_bounds__(256) void k_spmm(const unsigned* __restrict__ rec,
                                              const unsigned* __restrict__ cnt,
                                              const unsigned short* __restrict__ cols,
                                              const float* __restrict__ uvec,
                                              const float* __restrict__ b_g,
                                              const int* __restrict__ target,
                                              float* __restrict__ wr_,
                                              float* __restrict__ pr_,
                                              float* __restrict__ nlr,
                                              float* __restrict__ tgt) {
    const int lane = threadIdx.x & 63, wv = threadIdx.x >> 6;
    const int r = blockIdx.x * 4 + wv;
    const float u0 = uvec[lane], u1 = uvec[64 + lane], ub = uvec[128 + lane];
    const float bg = b_g[lane];
    int tg[B];
#pragma unroll
    for (int b = 0; b < B; ++b) tg[b] = target[b];

    const unsigned vown = rec[(size_t)r * 64 + lane];
    float2 fown = __half22float2(*(const __half2*)&vown);   // .y = disP, .x = aux

    float spA = fown.y, sxA = fown.x, spB = 0.f, sxB = 0.f;  // eye term in A
    const int kc = min((int)cnt[r], MAXDEG);
    const unsigned short* cl = &cols[r * MAXDEG];
    int k = 0;
#pragma unroll 2
    for (; k + 2 <= kc; k += 2) {                // 2 indep chains -> 4+ loads in flight
        int cA = cl[k], cB = cl[k + 1];
        unsigned vA = rec[(size_t)cA * 64 + lane];
        unsigned vB = rec[(size_t)cB * 64 + lane];
        float2 fA = __half22float2(*(const __half2*)&vA);
        float2 fB = __half22float2(*(const __half2*)&vB);
        spA += fA.y; sxA += fA.x;
        spB += fB.y; sxB += fB.x;
    }
    if (k < kc) {
        int c = cl[k];
        unsigned v = rec[(size_t)c * 64 + lane];
        float2 f = __half22float2(*(const __half2*)&v);
        spA += f.y; sxA += f.x;
    }
    const float sp = spA + spB;
    const float sx = sxA + sxB;

    const float dis_r = __shfl(fown.x, 16, 64);
    const float rdis = 1.0f / dis_r;
    const float sd = __shfl(sx, 16, 64);
    const float base = fmaf(sd, ub, sp);
    float wa[B], pa[B];
#pragma unroll
    for (int b = 0; b < B; ++b) {
        float sx0 = __shfl(sx, b, 64);
        float sx1 = __shfl(sx, 8 + b, 64);
        float sc  = __shfl(fown.x, 8 + b, 64) * rdis;   // score = x1[b][r]
        float mk  = __shfl(fown.x, 17 + b, 64);         // pmask[b][r]
        float v = fmaf(sx0, u0, fmaf(sx1, u1, base));
        float z = fmaxf(fmaf(dis_r, v, bg), 0.f);
        wa[b] = z * sc;
        pa[b] = (z + __logf(1.f + __expf(-z))) * mk;    // softplus, z>=0 stable
        if (r == tg[b]) tgt[b * H + lane] = z;
    }
    const int rep = r & (REPS - 1);
#pragma unroll
    for (int b = 0; b < B; ++b) {
        atomicAdd(&wr_[(rep * B + b) * H + lane], wa[b]);
        atomicAdd(&pr_[(rep * B + b) * H + lane], pa[b]);
    }
    if (lane < 8) atomicAdd(&nlr[rep * 8 + lane], fown.x * rdis);  // x0[b][r]
}

// K4: reduce replicas, per-batch dots, sigmoid
__global__ __launch_bounds__(512) void k_final(const float* __restrict__ wr_,
                                               const float* __restrict__ pr_,
                                               const float* __restrict__ nlr,
                                               const float* __restrict__ tgt,
                                               const float* __restrict__ W_d,
                                               const float* __restrict__ b_d,
                                               const float* __restrict__ W_a,
                                               const float* __restrict__ b_a,
                                               const float* __restrict__ prereq_w,
                                               float* __restrict__ out) {
    int tid = threadIdx.x, b = tid >> 6, h = tid & 63;
    float ws = 0.f, ps = 0.f, nlv = 0.f;
#pragma unroll
    for (int rep = 0; rep < REPS; ++rep) {
        ws  += wr_[(rep * B + b) * H + h];
        ps  += pr_[(rep * B + b) * H + h];
        nlv += nlr[rep * 8 + b];
    }
    float nl = fmaxf(nlv, 1.0f);
    float ap = (ws / nl) * W_a[h];
    float dp = tgt[b * H + h] * W_d[h];
    float pp = ps;
    for (int off = 32; off; off >>= 1) {
        ap += __shfl_down(ap, off, 64);
        dp += __shfl_down(dp, off, 64);
        pp += __shfl_down(pp, off, 64);
    }
    if (h == 0) {
        float ability    = ap + b_a[0];
        float difficulty = dp + b_d[0];
        float preq       = fabsf(prereq_w[0]) * (pp * (1.0f / (float)H));
        float gap  = ability - difficulty + preq;
        float prob = 1.0f / (1.0f + __expf(-gap));
        out[b]     = prob;
        out[B + b] = gap;
    }
}

extern "C" void kernel_launch(void* const* d_in, const int* in_sizes, int n_in,
                              void* d_out, int out_size, void* d_ws, size_t ws_size,
                              hipStream_t stream) {
    const float* x        = (const float*)d_in[0];
    const int*   ei       = (const int*)d_in[1];
    const int*   target   = (const int*)d_in[2];
    const float* pmask    = (const float*)d_in[3];
    const float* ne       = (const float*)d_in[4];
    const float* W_sp     = (const float*)d_in[5];
    const float* b_sp     = (const float*)d_in[6];
    const float* W_g      = (const float*)d_in[7];
    const float* b_g      = (const float*)d_in[8];
    const float* W_d      = (const float*)d_in[9];
    const float* b_d      = (const float*)d_in[10];
    const float* W_a      = (const float*)d_in[11];
    const float* b_a      = (const float*)d_in[12];
    const float* prereq_w = (const float*)d_in[13];

    const int nE = in_sizes[1] / 2;

    char* ws = (char*)d_ws;
    unsigned*        cnt  = (unsigned*)(ws + OFF_CNT);
    float*           wr_  = (float*)(ws + OFF_WR);
    float*           pr_  = (float*)(ws + OFF_PR);
    float*           nlr  = (float*)(ws + OFF_NLR);
    unsigned short*  cols = (unsigned short*)(ws + OFF_COLS);
    float*           tgt  = (float*)(ws + OFF_TGT);
    float*           uvec = (float*)(ws + OFF_UV);
    unsigned*        rec  = (unsigned*)(ws + OFF_REC);

    // ws poisoned 0xAA once, never re-poisoned between replays -> zero every call
    k_zero<<<(unsigned)(ZERO_END / 16 + 255) / 256, 256, 0, stream>>>((float4*)ws);
    k_edges<<<(nE + 255) / 256, 256, 0, stream>>>(ei, nE, cnt, cols);
    k_prep<<<N / 8, 256, 0, stream>>>(ne, W_g, W_sp, b_sp, x, pmask, cnt, cols,
                                      rec, uvec);
    k_spmm<<<N / 4, 256, 0, stream>>>(rec, cnt, cols, uvec, b_g, target,
                                      wr_, pr_, nlr, tgt);
    k_final<<<1, 512, 0, stream>>>(wr_, pr_, nlr, tgt, W_d, b_d, W_a, b_a,
                                   prereq_w, (float*)d_out);
}

// Round 11
// 89.922 us; speedup vs baseline: 3.1433x; 1.0399x over previous
//
#include <hip/hip_runtime.h>
#include <hip/hip_fp16.h>
#include <math.h>

#define N 8192
#define H 64
#define B 8
#define MAXDEG 128
#define REPS 8

// ---- workspace layout (bytes) ----
// zeroed each call by k_zero:
#define OFF_CNT  0ULL            // 8192 u32 = 32768
#define OFF_WR   32768ULL        // REPS*8*64 f32 = 16384
#define OFF_PR   49152ULL        // 16384
#define OFF_NLR  65536ULL        // REPS*8 f32 = 256
#define ZERO_END 65792ULL        // /16 = 4112 float4
// not zeroed:
#define OFF_COLS 65792ULL        // 8192*128 u16 = 2,097,152
#define OFF_TGT  2162944ULL      // 512 f32 = 2048
#define OFF_UV   2164992ULL      // 3*64 f32 = 768
#define OFF_REC  2165760ULL      // 8192*64 u32 = 2,097,152 (256B-aligned)
// end ~4.3 MB

// K0: zero cnt + replica accumulators (~64 KB)
__global__ __launch_bounds__(256) void k_zero(float4* __restrict__ p) {
    unsigned i = blockIdx.x * 256u + threadIdx.x;
    if (i < (unsigned)(ZERO_END / 16))
        p[i] = make_float4(0.f, 0.f, 0.f, 0.f);
}

// K1: append edges (1 edge/thread; dedup in K2)
__global__ __launch_bounds__(256) void k_edges(const int* __restrict__ ei, int nE,
                                               unsigned* __restrict__ cnt,
                                               unsigned short* __restrict__ cols) {
    int e = blockIdx.x * 256 + threadIdx.x;
    if (e >= nE) return;
    int r = ei[e];
    int c = ei[nE + e];
    unsigned k = atomicAdd(&cnt[r], 1u);
    if (k < MAXDEG) cols[r * MAXDEG + k] = (unsigned short)c;
}

// K2: per-wave {dedup -> dis -> packed record} for 2 rows; uvec on blk0/wv0.
// rec[m][lane] u32 = f16(dis_m * (W_g@ne[m])_lane) << 16 | f16(aux_lane)
// aux: lane<8: dis*x0_b; 8..15: dis*x1_b; 16: dis; 17..24: pmask_b; else 0.
__global__ __launch_bounds__(256) void k_prep(const float* __restrict__ ne,
                                              const float* __restrict__ W_g,
                                              const float* __restrict__ W_sp,
                                              const float* __restrict__ b_sp,
                                              const float* __restrict__ x,
                                              const float* __restrict__ pmask,
                                              unsigned* __restrict__ cnt,
                                              unsigned short* __restrict__ cols,
                                              unsigned* __restrict__ rec,
                                              float* __restrict__ uvec) {
    __shared__ float wgs[H * 65];                // padded W_g
    __shared__ unsigned short ls[4][MAXDEG];     // dedup staging
    const int tid = threadIdx.x, lane = tid & 63, wv = tid >> 6;
    const int bid = blockIdx.x;

    for (int e = tid; e < H * H; e += 256)
        wgs[(e >> 6) * 65 + (e & 63)] = W_g[e];
    __syncthreads();

    float wr[H];
#pragma unroll
    for (int k = 0; k < H; ++k) wr[k] = wgs[lane * 65 + k];

    if (bid == 0 && wv == 0) {   // uvec = {W_g@Wsp0, W_g@Wsp1, W_g@b_sp}
        float v0 = W_sp[lane * 2 + 0], v1 = W_sp[lane * 2 + 1], vb = b_sp[lane];
        float a0 = 0.f, a1 = 0.f, a2 = 0.f;
#pragma unroll
        for (int k = 0; k < H; ++k) {
            a0 = fmaf(wr[k], __shfl(v0, k, 64), a0);
            a1 = fmaf(wr[k], __shfl(v1, k, 64), a1);
            a2 = fmaf(wr[k], __shfl(vb, k, 64), a2);
        }
        uvec[lane] = a0; uvec[64 + lane] = a1; uvec[128 + lane] = a2;
    }

    for (int i = 0; i < 2; ++i) {
        const int r = (bid * 4 + wv) * 2 + i;
        // --- dedup row r ---
        const int kraw = min((int)cnt[r], MAXDEG);
        unsigned short* cl = &cols[r * MAXDEG];
        for (int t = lane; t < kraw; t += 64) ls[wv][t] = cl[t];
        int c0 = (lane < kraw) ? (int)ls[wv][lane] : -1;
        int dup0 = 0;
        for (int j = 0; j < lane && j < kraw; ++j)
            dup0 |= ((int)ls[wv][j] == c0);
        unsigned long long m0 = __ballot((lane < kraw) && !dup0);
        unsigned long long below = (1ULL << lane) - 1ULL;
        unsigned tot = __popcll(m0);
        if ((lane < kraw) && !dup0)
            cl[__popcll(m0 & below)] = (unsigned short)c0;
        if (kraw > 64) {                          // wave-uniform, rare
            const int i1 = lane + 64;
            int c1 = (i1 < kraw) ? (int)ls[wv][i1] : -2;
            int dup1 = 0;
            for (int j = 0; j < i1 && j < kraw; ++j)
                dup1 |= ((int)ls[wv][j] == c1);
            unsigned long long m1 = __ballot((i1 < kraw) && !dup1);
            if ((i1 < kraw) && !dup1)
                cl[tot + __popcll(m1 & below)] = (unsigned short)c1;
            tot += __popcll(m1);
        }
        if (lane == 0) cnt[r] = tot;
        const float dis = rsqrtf((float)(tot + 1u));

        // --- aux for row r ---
        float xvx = 0.f, xvy = 0.f, pm = 0.f;
        if (lane < 8) {
            float2 t2 = ((const float2*)x)[lane * N + r];
            xvx = t2.x; xvy = t2.y;
        }
        if (lane >= 17 && lane < 25) pm = pmask[(lane - 17) * N + r];
        float yv = __shfl(xvy, lane & 7, 64);
        float aux = (lane < 8)   ? dis * xvx
                  : (lane < 16)  ? dis * yv
                  : (lane == 16) ? dis
                  : (lane < 25)  ? pm : 0.f;

        // --- P part: dis * (W_g @ ne[r])_lane ---
        const float4* ne4 = (const float4*)(ne + (size_t)r * H);
        float acc = 0.f;
#pragma unroll
        for (int kk = 0; kk < 16; ++kk) {
            float4 h4 = ne4[kk];
            acc = fmaf(wr[4 * kk + 0], h4.x, acc);
            acc = fmaf(wr[4 * kk + 1], h4.y, acc);
            acc = fmaf(wr[4 * kk + 2], h4.z, acc);
            acc = fmaf(wr[4 * kk + 3], h4.w, acc);
        }
        unsigned w = ((unsigned)__half_as_ushort(__float2half(dis * acc)) << 16)
                   |  (unsigned)__half_as_ushort(__float2half(aux));
        rec[(size_t)r * 64 + lane] = w;
    }
}

// K3: gather phase. 512 blocks x 1024 thr (16 waves), 1 row/wave = 8192 waves.
// Col list loaded cooperatively once (shfl-broadcast in loop). Per-block LDS
// accumulation -> 1 global atomic per element per block (16x fewer lane-atomics).
__global__ __launch_bounds__(1024, 2) void k_spmm(const unsigned* __restrict__ rec,
                                                  const unsigned* __restrict__ cnt,
                                                  const unsigned short* __restrict__ cols,
                                                  const float* __restrict__ uvec,
                                                  const float* __restrict__ b_g,
                                                  const int* __restrict__ target,
                                                  float* __restrict__ wr_,
                                                  float* __restrict__ pr_,
                                                  float* __restrict__ nlr,
                                                  float* __restrict__ tgt) {
    __shared__ float lw[B * H];      // block partial: weighted_z
    __shared__ float lp[B * H];      // block partial: prereq
    __shared__ float lnl[B];         // block partial: n_learned
    const int tid = threadIdx.x;
    const int lane = tid & 63, wv = tid >> 6;
    const int r = blockIdx.x * 16 + wv;

    if (tid < B * H) { lw[tid] = 0.f; lp[tid] = 0.f; }
    if (tid < B) lnl[tid] = 0.f;
    __syncthreads();

    const float u0 = uvec[lane], u1 = uvec[64 + lane], ub = uvec[128 + lane];
    const float bg = b_g[lane];
    int tg[B];
#pragma unroll
    for (int b = 0; b < B; ++b) tg[b] = target[b];

    const unsigned vown = rec[(size_t)r * 64 + lane];
    float2 fown = __half22float2(*(const __half2*)&vown);   // .y = disP, .x = aux

    const int kc = min((int)cnt[r], MAXDEG);
    const unsigned short* cl = &cols[r * MAXDEG];
    // cooperative col load: one coalesced read covers k < 64
    int creg = (lane < kc) ? (int)cl[lane] : 0;

    float spA = fown.y, sxA = fown.x, spB = 0.f, sxB = 0.f;  // eye term in A
    const int kc64 = min(kc, 64);
    int k = 0;
    for (; k + 2 <= kc64; k += 2) {              // 2 indep chains, no col loads
        int cA = __shfl(creg, k, 64);
        int cB = __shfl(creg, k + 1, 64);
        unsigned vA = rec[(size_t)cA * 64 + lane];
        unsigned vB = rec[(size_t)cB * 64 + lane];
        float2 fA = __half22float2(*(const __half2*)&vA);
        float2 fB = __half22float2(*(const __half2*)&vB);
        spA += fA.y; sxA += fA.x;
        spB += fB.y; sxB += fB.x;
    }
    if (k < kc64) {
        int c = __shfl(creg, k, 64);
        unsigned v = rec[(size_t)c * 64 + lane];
        float2 f = __half22float2(*(const __half2*)&v);
        spA += f.y; sxA += f.x;
    }
    for (int kk = 64; kk < kc; ++kk) {           // rare tail (deg > 64)
        int c = (int)cl[kk];
        unsigned v = rec[(size_t)c * 64 + lane];
        float2 f = __half22float2(*(const __half2*)&v);
        spA += f.y; sxA += f.x;
    }
    const float sp = spA + spB;
    const float sx = sxA + sxB;

    const float dis_r = __shfl(fown.x, 16, 64);
    const float rdis = 1.0f / dis_r;
    const float sd = __shfl(sx, 16, 64);
    const float base = fmaf(sd, ub, sp);
#pragma unroll
    for (int b = 0; b < B; ++b) {
        float sx0 = __shfl(sx, b, 64);
        float sx1 = __shfl(sx, 8 + b, 64);
        float sc  = __shfl(fown.x, 8 + b, 64) * rdis;   // score = x1[b][r]
        float mk  = __shfl(fown.x, 17 + b, 64);         // pmask[b][r]
        float v = fmaf(sx0, u0, fmaf(sx1, u1, base));
        float z = fmaxf(fmaf(dis_r, v, bg), 0.f);
        atomicAdd(&lw[b * H + lane], z * sc);
        atomicAdd(&lp[b * H + lane], (z + __logf(1.f + __expf(-z))) * mk);
        if (r == tg[b]) tgt[b * H + lane] = z;
    }
    if (lane < 8) atomicAdd(&lnl[lane], fown.x * rdis);  // x0[b][r]
    __syncthreads();

    // block -> global: one atomic per element
    const int rep = blockIdx.x & (REPS - 1);
    if (tid < B * H)           atomicAdd(&wr_[rep * B * H + tid], lw[tid]);
    else if (tid < 2 * B * H)  atomicAdd(&pr_[rep * B * H + tid - B * H], lp[tid - B * H]);
    if (tid < B)               atomicAdd(&nlr[rep * B + tid], lnl[tid]);
}

// K4: reduce replicas, per-batch dots, sigmoid
__global__ __launch_bounds__(512) void k_final(const float* __restrict__ wr_,
                                               const float* __restrict__ pr_,
                                               const float* __restrict__ nlr,
                                               const float* __restrict__ tgt,
                                               const float* __restrict__ W_d,
                                               const float* __restrict__ b_d,
                                               const float* __restrict__ W_a,
                                               const float* __restrict__ b_a,
                                               const float* __restrict__ prereq_w,
                                               float* __restrict__ out) {
    int tid = threadIdx.x, b = tid >> 6, h = tid & 63;
    float ws = 0.f, ps = 0.f, nlv = 0.f;
#pragma unroll
    for (int rep = 0; rep < REPS; ++rep) {
        ws  += wr_[(rep * B + b) * H + h];
        ps  += pr_[(rep * B + b) * H + h];
        nlv += nlr[rep * B + b];
    }
    float nl = fmaxf(nlv, 1.0f);
    float ap = (ws / nl) * W_a[h];
    float dp = tgt[b * H + h] * W_d[h];
    float pp = ps;
    for (int off = 32; off; off >>= 1) {
        ap += __shfl_down(ap, off, 64);
        dp += __shfl_down(dp, off, 64);
        pp += __shfl_down(pp, off, 64);
    }
    if (h == 0) {
        float ability    = ap + b_a[0];
        float difficulty = dp + b_d[0];
        float preq       = fabsf(prereq_w[0]) * (pp * (1.0f / (float)H));
        float gap  = ability - difficulty + preq;
        float prob = 1.0f / (1.0f + __expf(-gap));
        out[b]     = prob;
        out[B + b] = gap;
    }
}

extern "C" void kernel_launch(void* const* d_in, const int* in_sizes, int n_in,
                              void* d_out, int out_size, void* d_ws, size_t ws_size,
                              hipStream_t stream) {
    const float* x        = (const float*)d_in[0];
    const int*   ei       = (const int*)d_in[1];
    const int*   target   = (const int*)d_in[2];
    const float* pmask    = (const float*)d_in[3];
    const float* ne       = (const float*)d_in[4];
    const float* W_sp     = (const float*)d_in[5];
    const float* b_sp     = (const float*)d_in[6];
    const float* W_g      = (const float*)d_in[7];
    const float* b_g      = (const float*)d_in[8];
    const float* W_d      = (const float*)d_in[9];
    const float* b_d      = (const float*)d_in[10];
    const float* W_a      = (const float*)d_in[11];
    const float* b_a      = (const float*)d_in[12];
    const float* prereq_w = (const float*)d_in[13];

    const int nE = in_sizes[1] / 2;

    char* ws = (char*)d_ws;
    unsigned*        cnt  = (unsigned*)(ws + OFF_CNT);
    float*           wr_  = (float*)(ws + OFF_WR);
    float*           pr_  = (float*)(ws + OFF_PR);
    float*           nlr  = (float*)(ws + OFF_NLR);
    unsigned short*  cols = (unsigned short*)(ws + OFF_COLS);
    float*           tgt  = (float*)(ws + OFF_TGT);
    float*           uvec = (float*)(ws + OFF_UV);
    unsigned*        rec  = (unsigned*)(ws + OFF_REC);

    // ws poisoned 0xAA once, never re-poisoned between replays -> zero every call
    k_zero<<<(unsigned)(ZERO_END / 16 + 255) / 256, 256, 0, stream>>>((float4*)ws);
    k_edges<<<(nE + 255) / 256, 256, 0, stream>>>(ei, nE, cnt, cols);
    k_prep<<<N / 8, 256, 0, stream>>>(ne, W_g, W_sp, b_sp, x, pmask, cnt, cols,
                                      rec, uvec);
    k_spmm<<<N / 16, 1024, 0, stream>>>(rec, cnt, cols, uvec, b_g, target,
                                        wr_, pr_, nlr, tgt);
    k_final<<<1, 512, 0, stream>>>(wr_, pr_, nlr, tgt, W_d, b_d, W_a, b_a,
                                   prereq_w, (float*)d_out);
}